// Round 1
// baseline (474.735 us; speedup 1.0000x reference)
//
#include <hip/hip_runtime.h>
#include <cstddef>

#define B_   8
#define C_   64
#define H_   96
#define W_   96
#define O_   64
#define HW_  (H_*W_)        // 9216
#define PIX_ (B_*HW_)       // 73728

// ws layout (float offsets)
#define XT_OFF   0
#define XT_SZ    (PIX_*C_)            // 4,718,592 floats (NHWC x)
#define META_OFF (XT_OFF + XT_SZ)
#define META_SZ  (PIX_*9*8)           // 5,308,416 words: [pix][n]{int4 idx, float4 g}
#define AWT_OFF  (META_OFF + META_SZ)
#define AWT_SZ   (576*32)             // offset/mod weights as [c*9+t][j(pad32)]
#define CWT_OFF  (AWT_OFF + AWT_SZ)
#define CWT_SZ   (576*64)             // conv weights as [c*9+n][o]

// ---------------------------------------------------------------------------
// NCHW -> NHWC transpose of x via LDS tile (64 spatial x 64 channels)
__global__ __launch_bounds__(256) void k_transpose(const float* __restrict__ x,
                                                   float* __restrict__ xt) {
    __shared__ float tile[64 * 65];   // +1 pad: conflict-free both phases
    int bb  = blockIdx.x / 144;
    int sp0 = (blockIdx.x % 144) * 64;
    int t = threadIdx.x;
    int s = t & 63, cg = t >> 6;
    #pragma unroll
    for (int i = 0; i < 16; ++i) {
        int c = cg * 16 + i;
        tile[c * 65 + s] = x[(size_t)(bb * C_ + c) * HW_ + sp0 + s];
    }
    __syncthreads();
    int cl = t & 63, sg = t >> 6;
    #pragma unroll
    for (int i = 0; i < 16; ++i) {
        int s2 = sg * 16 + i;
        xt[(size_t)(bb * HW_ + sp0 + s2) * 64 + cl] = tile[cl * 65 + s2];
    }
}

// ---------------------------------------------------------------------------
// Weight repack: awt[(c*9+t)*32 + j] (j<18 offset_w, 18<=j<27 m_w, pad 0)
//                cwt[(c*9+n)*64 + o]
__global__ __launch_bounds__(256) void k_prepw(const float* __restrict__ offw,
                                               const float* __restrict__ mw,
                                               const float* __restrict__ convw,
                                               float* __restrict__ awt,
                                               float* __restrict__ cwt) {
    int tid = blockIdx.x * 256 + threadIdx.x;
    if (tid < AWT_SZ) {
        int j = tid & 31, ct = tid >> 5;      // ct = c*9+t in [0,576)
        float v = 0.f;
        if (j < 18)      v = offw[j * 576 + ct];
        else if (j < 27) v = mw[(j - 18) * 576 + ct];
        awt[tid] = v;
    }
    int k = tid - AWT_SZ;
    if (k >= 0 && k < CWT_SZ) {
        int o = k & 63, cn = k >> 6;
        cwt[k] = convw[o * 576 + cn];
    }
}

// ---------------------------------------------------------------------------
// Offset/mod 3x3 conv fused with bilinear metadata generation.
// One thread per output pixel; 28 accumulators (27 used).
__global__ __launch_bounds__(256, 4) void k_offs(const float* __restrict__ x,
                                                 const float* __restrict__ offb,
                                                 const float* __restrict__ mb,
                                                 const float* __restrict__ awt,
                                                 float* __restrict__ meta) {
    int pix = blockIdx.x * 256 + threadIdx.x;
    int b = pix / HW_, s = pix % HW_;
    int hh = s / W_, ww = s % W_;

    float accs[28];
    #pragma unroll
    for (int j = 0; j < 28; ++j)
        accs[j] = (j < 18) ? offb[j] : ((j < 27) ? mb[j - 18] : 0.f);

    const float* xb = x + (size_t)b * C_ * HW_;
    #pragma unroll 1
    for (int c = 0; c < C_; ++c) {
        const float* xc = xb + c * HW_;
        float xv[9];
        #pragma unroll
        for (int kh = 0; kh < 3; ++kh) {
            int y = hh - 1 + kh;
            #pragma unroll
            for (int kw = 0; kw < 3; ++kw) {
                int xx = ww - 1 + kw;
                bool ok = (y >= 0) && (y < H_) && (xx >= 0) && (xx < W_);
                xv[kh * 3 + kw] = ok ? xc[y * W_ + xx] : 0.f;
            }
        }
        const float4* wp = (const float4*)(awt + c * 9 * 32);
        #pragma unroll
        for (int t = 0; t < 9; ++t) {
            float xvt = xv[t];
            #pragma unroll
            for (int jq = 0; jq < 7; ++jq) {
                float4 wv = wp[t * 8 + jq];
                accs[jq * 4 + 0] += wv.x * xvt;
                accs[jq * 4 + 1] += wv.y * xvt;
                accs[jq * 4 + 2] += wv.z * xvt;
                accs[jq * 4 + 3] += wv.w * xvt;
            }
        }
    }

    // Bilinear metadata: padded coords Hp=Wp=98; interior (1..96) maps to x.
    float* mp = meta + (size_t)pix * 72;
    #pragma unroll
    for (int n = 0; n < 9; ++n) {
        float mod = 1.f / (1.f + __expf(-accs[18 + n]));
        float px = accs[n]     + (float)(hh + 1) + (float)(n / 3 - 1);
        float py = accs[9 + n] + (float)(ww + 1) + (float)(n % 3 - 1);
        float flx = floorf(px), fly = floorf(py);
        float tlxf = fminf(fmaxf(flx,       0.f), 97.f);
        float tlyf = fminf(fmaxf(fly,       0.f), 97.f);
        float brxf = fminf(fmaxf(flx + 1.f, 0.f), 97.f);
        float bryf = fminf(fmaxf(fly + 1.f, 0.f), 97.f);
        float pcx  = fminf(fmaxf(px, 0.f), 97.f);
        float pcy  = fminf(fmaxf(py, 0.f), 97.f);
        float gx0 = 1.f + tlxf - pcx;      // (1 + (tlx - pcx))
        float gx1 = 1.f - (brxf - pcx);
        float gy0 = 1.f + tlyf - pcy;
        float gy1 = 1.f - (bryf - pcy);
        int tlx = (int)tlxf, tly = (int)tlyf, brx = (int)brxf, bry = (int)bryf;

        int   qxs[4] = {tlx, tlx, brx, brx};
        int   qys[4] = {tly, bry, tly, bry};
        float gs[4]  = {gx0 * gy0, gx0 * gy1, gx1 * gy0, gx1 * gy1};
        int   idx[4]; float gg[4];
        #pragma unroll
        for (int q = 0; q < 4; ++q) {
            bool ok = (qxs[q] >= 1) && (qxs[q] <= 96) && (qys[q] >= 1) && (qys[q] <= 96);
            idx[q] = ok ? ((qxs[q] - 1) * W_ + (qys[q] - 1)) : 0;  // idx 0 is safe
            gg[q]  = ok ? gs[q] * mod : 0.f;
        }
        int4 iv;  iv.x = idx[0]; iv.y = idx[1]; iv.z = idx[2]; iv.w = idx[3];
        float4 gv; gv.x = gg[0]; gv.y = gg[1]; gv.z = gg[2]; gv.w = gg[3];
        *(int4*)  (mp + n * 8)     = iv;
        *(float4*)(mp + n * 8 + 4) = gv;
    }
}

// ---------------------------------------------------------------------------
// Main: gather (NHWC, coalesced) + contraction. lane = pixel, 64 accs = all O.
__global__ __launch_bounds__(64, 2) void k_main(const float* __restrict__ xt,
                                                const float* __restrict__ meta,
                                                const float* __restrict__ cwt,
                                                const float* __restrict__ convb,
                                                float* __restrict__ out) {
    int lane = threadIdx.x;
    int pix = blockIdx.x * 64 + lane;
    int b = pix / HW_, s = pix % HW_;
    const float* xtb = xt + (size_t)b * HW_ * 64;

    float accs[64];
    #pragma unroll
    for (int i = 0; i < 64; ++i) accs[i] = 0.f;

    const float* mp = meta + (size_t)pix * 72;
    #pragma unroll 1
    for (int n = 0; n < 9; ++n) {
        int4   idx = *(const int4*)  (mp + n * 8);
        float4 g   = *(const float4*)(mp + n * 8 + 4);
        const float* p0 = xtb + (size_t)idx.x * 64;
        const float* p1 = xtb + (size_t)idx.y * 64;
        const float* p2 = xtb + (size_t)idx.z * 64;
        const float* p3 = xtb + (size_t)idx.w * 64;
        #pragma unroll 1
        for (int ch = 0; ch < 4; ++ch) {
            int co = ch * 16;
            float xs[16];
            #pragma unroll
            for (int q = 0; q < 4; ++q) {
                float4 v0 = *(const float4*)(p0 + co + q * 4);
                float4 v1 = *(const float4*)(p1 + co + q * 4);
                float4 v2 = *(const float4*)(p2 + co + q * 4);
                float4 v3 = *(const float4*)(p3 + co + q * 4);
                xs[q * 4 + 0] = g.x * v0.x + g.y * v1.x + g.z * v2.x + g.w * v3.x;
                xs[q * 4 + 1] = g.x * v0.y + g.y * v1.y + g.z * v2.y + g.w * v3.y;
                xs[q * 4 + 2] = g.x * v0.z + g.y * v1.z + g.z * v2.z + g.w * v3.z;
                xs[q * 4 + 3] = g.x * v0.w + g.y * v1.w + g.z * v2.w + g.w * v3.w;
            }
            #pragma unroll
            for (int cs = 0; cs < 16; ++cs) {
                float xv = xs[cs];
                const float4* wp = (const float4*)(cwt + (size_t)((co + cs) * 9 + n) * 64);
                #pragma unroll
                for (int oq = 0; oq < 16; ++oq) {
                    float4 wv = wp[oq];
                    accs[oq * 4 + 0] += wv.x * xv;
                    accs[oq * 4 + 1] += wv.y * xv;
                    accs[oq * 4 + 2] += wv.z * xv;
                    accs[oq * 4 + 3] += wv.w * xv;
                }
            }
        }
    }

    float* ob = out + (size_t)b * O_ * HW_ + s;
    #pragma unroll
    for (int o = 0; o < 64; ++o)
        ob[(size_t)o * HW_] = accs[o] + convb[o];
}

// ---------------------------------------------------------------------------
extern "C" void kernel_launch(void* const* d_in, const int* in_sizes, int n_in,
                              void* d_out, int out_size, void* d_ws, size_t ws_size,
                              hipStream_t stream) {
    const float* x     = (const float*)d_in[0];
    const float* offw  = (const float*)d_in[1];
    const float* offb  = (const float*)d_in[2];
    const float* mw    = (const float*)d_in[3];
    const float* mb    = (const float*)d_in[4];
    const float* convw = (const float*)d_in[5];
    const float* convb = (const float*)d_in[6];
    float* ws   = (float*)d_ws;
    float* xt   = ws + XT_OFF;
    float* meta = ws + META_OFF;
    float* awt  = ws + AWT_OFF;
    float* cwt  = ws + CWT_OFF;
    float* out  = (float*)d_out;

    k_transpose<<<dim3(1152), dim3(256), 0, stream>>>(x, xt);
    k_prepw    <<<dim3(216),  dim3(256), 0, stream>>>(offw, mw, convw, awt, cwt);
    k_offs     <<<dim3(288),  dim3(256), 0, stream>>>(x, offb, mb, awt, meta);
    k_main     <<<dim3(1152), dim3(64),  0, stream>>>(xt, meta, cwt, convb, out);
}

// Round 2
// 175.109 us; speedup vs baseline: 2.7111x; 2.7111x over previous
//
#include <hip/hip_runtime.h>
#include <cstddef>

#define B_   8
#define C_   64
#define H_   96
#define W_   96
#define O_   64
#define HW_  (H_*W_)        // 9216
#define PIX_ (B_*HW_)       // 73728

typedef __attribute__((ext_vector_type(8))) __bf16 bf16x8;
typedef __attribute__((ext_vector_type(4))) float floatx4;
typedef __attribute__((ext_vector_type(8))) unsigned short ushort8;

// ws layout (byte offsets)
#define XT_OFF    0                         // bf16 NHWC x: PIX*64*2 = 9,437,184 B
#define META_OFF  (XT_OFF + PIX_*64*2)      // [pix][n]{int4,float4}: PIX*72*4 B
#define WFM_OFF   (META_OFF + PIX_*72*4)    // main W frags: 18*4*64*8 bf16 = 73,728 B
#define WFO_OFF   (WFM_OFF + 18*4*64*8*2)   // offs W frags: 18*2*64*8 bf16 = 36,864 B

__device__ __forceinline__ unsigned short f2bf(float f) {
    unsigned u = __float_as_uint(f);
    return (unsigned short)((u + 0x7FFFu + ((u >> 16) & 1u)) >> 16);
}
__device__ __forceinline__ float bf2f(unsigned short v) {
    return __uint_as_float((unsigned)v << 16);
}

// ---------------------------------------------------------------------------
// NCHW f32 -> NHWC bf16 transpose via LDS tile
__global__ __launch_bounds__(256) void k_transpose(const float* __restrict__ x,
                                                   unsigned short* __restrict__ xt) {
    __shared__ float tile[64 * 65];
    int bb  = blockIdx.x / 144;
    int sp0 = (blockIdx.x % 144) * 64;
    int t = threadIdx.x;
    int s = t & 63, cg = t >> 6;
    #pragma unroll
    for (int i = 0; i < 16; ++i) {
        int c = cg * 16 + i;
        tile[c * 65 + s] = x[(size_t)(bb * C_ + c) * HW_ + sp0 + s];
    }
    __syncthreads();
    int cl2 = (t & 31) * 2, sg = t >> 5;
    #pragma unroll
    for (int i = 0; i < 8; ++i) {
        int s2 = sg * 8 + i;
        float f0 = tile[cl2 * 65 + s2];
        float f1 = tile[(cl2 + 1) * 65 + s2];
        unsigned wd = (unsigned)f2bf(f0) | ((unsigned)f2bf(f1) << 16);
        *(unsigned*)(xt + (size_t)(bb * HW_ + sp0 + s2) * 64 + cl2) = wd;
    }
}

// ---------------------------------------------------------------------------
// Pack weights into MFMA A-fragment order (k = tap*64 + c).
// wfm[((ks*4+mt)*64+lane)*8 + j] = bf16 convw[o=mt*16+(lane&15)][k=ks*32+(lane>>4)*8+j]
// wfo analogous with mt in [0,2), m<18 offset_w, 18..26 m_w, else 0.
__global__ __launch_bounds__(256) void k_prepw(const float* __restrict__ offw,
                                               const float* __restrict__ mw,
                                               const float* __restrict__ convw,
                                               unsigned short* __restrict__ wfm,
                                               unsigned short* __restrict__ wfo) {
    int g = blockIdx.x * 256 + threadIdx.x;
    if (g < 4608) {
        int lane = g & 63, mtks = g >> 6;
        int mt = mtks & 3, ks = mtks >> 2;
        int o = mt * 16 + (lane & 15), quad = lane >> 4;
        unsigned v[8];
        #pragma unroll
        for (int j = 0; j < 8; ++j) {
            int k = ks * 32 + quad * 8 + j;
            int t = k / 64, c = k % 64;
            v[j] = f2bf(convw[(size_t)(o * 64 + c) * 9 + t]);
        }
        uint4 pk;
        pk.x = v[0] | (v[1] << 16); pk.y = v[2] | (v[3] << 16);
        pk.z = v[4] | (v[5] << 16); pk.w = v[6] | (v[7] << 16);
        *(uint4*)(wfm + (size_t)g * 8) = pk;
    } else if (g < 4608 + 2304) {
        int g2 = g - 4608;
        int lane = g2 & 63, mtks = g2 >> 6;
        int mt = mtks & 1, ks = mtks >> 1;
        int m = mt * 16 + (lane & 15), quad = lane >> 4;
        unsigned v[8];
        #pragma unroll
        for (int j = 0; j < 8; ++j) {
            int k = ks * 32 + quad * 8 + j;
            int t = k / 64, c = k % 64;
            float f = 0.f;
            if (m < 18)      f = offw[(size_t)(m * 64 + c) * 9 + t];
            else if (m < 27) f = mw[(size_t)((m - 18) * 64 + c) * 9 + t];
            v[j] = f2bf(f);
        }
        uint4 pk;
        pk.x = v[0] | (v[1] << 16); pk.y = v[2] | (v[3] << 16);
        pk.z = v[4] | (v[5] << 16); pk.w = v[6] | (v[7] << 16);
        *(uint4*)(wfo + (size_t)g2 * 8) = pk;
    }
}

// ---------------------------------------------------------------------------
// Offset/mod conv as MFMA GEMM (M=32, K=576, N=64 pixels/block) + meta gen.
__global__ __launch_bounds__(256, 2) void k_offs2(const unsigned short* __restrict__ xt,
                                                  const unsigned short* __restrict__ wfo,
                                                  const float* __restrict__ offb,
                                                  const float* __restrict__ mb,
                                                  float* __restrict__ meta) {
    __shared__ unsigned short s_tile[64 * 72];
    __shared__ float s_off[32 * 64];
    int tid = threadIdx.x, blk = blockIdx.x;
    int b = blk / 144, s0 = (blk % 144) * 64;
    int p = tid & 63, q = tid >> 6;      // p = lane = pixel, q = wave = ch-quarter
    int s = s0 + p, hh = s / 96, ww = s % 96;
    const unsigned short* xtb = xt + (size_t)b * HW_ * 64;

    floatx4 acc0 = {0.f, 0.f, 0.f, 0.f}, acc1 = {0.f, 0.f, 0.f, 0.f};
    int lane = p, w = q, quad = lane >> 4;

    #pragma unroll 1
    for (int t = 0; t < 9; ++t) {
        int dh = t / 3 - 1, dw = t % 3 - 1;
        int h2 = hh + dh, w2 = ww + dw;
        bool ok = ((unsigned)h2 < 96u) && ((unsigned)w2 < 96u);
        uint4 v0 = make_uint4(0, 0, 0, 0), v1 = make_uint4(0, 0, 0, 0);
        if (ok) {
            const uint4* src = (const uint4*)(xtb + (size_t)(h2 * 96 + w2) * 64 + q * 16);
            v0 = src[0]; v1 = src[1];
        }
        __syncthreads();
        *(uint4*)&s_tile[p * 72 + q * 16]     = v0;
        *(uint4*)&s_tile[p * 72 + q * 16 + 8] = v1;
        __syncthreads();
        #pragma unroll
        for (int ksl = 0; ksl < 2; ++ksl) {
            int ks = t * 2 + ksl;
            bf16x8 bfrag = *(const bf16x8*)&s_tile[(w * 16 + (lane & 15)) * 72 + ksl * 32 + quad * 8];
            bf16x8 a0 = *(const bf16x8*)(wfo + ((size_t)(ks * 2 + 0) * 64 + lane) * 8);
            bf16x8 a1 = *(const bf16x8*)(wfo + ((size_t)(ks * 2 + 1) * 64 + lane) * 8);
            acc0 = __builtin_amdgcn_mfma_f32_16x16x32_bf16(a0, bfrag, acc0, 0, 0, 0);
            acc1 = __builtin_amdgcn_mfma_f32_16x16x32_bf16(a1, bfrag, acc1, 0, 0, 0);
        }
    }
    __syncthreads();
    {
        int pp = w * 16 + (lane & 15);
        #pragma unroll
        for (int r = 0; r < 4; ++r) {
            s_off[(quad * 4 + r) * 64 + pp]      = acc0[r];
            s_off[(16 + quad * 4 + r) * 64 + pp] = acc1[r];
        }
    }
    __syncthreads();

    float* mp = meta + (size_t)(blk * 64 + p) * 72;
    for (int n = q; n < 9; n += 4) {
        float ox  = s_off[n * 64 + p]        + offb[n];
        float oy  = s_off[(9 + n) * 64 + p]  + offb[9 + n];
        float mv  = s_off[(18 + n) * 64 + p] + mb[n];
        float mod = 1.f / (1.f + __expf(-mv));
        float px = ox + (float)(hh + 1) + (float)(n / 3 - 1);
        float py = oy + (float)(ww + 1) + (float)(n % 3 - 1);
        float flx = floorf(px), fly = floorf(py);
        float tlxf = fminf(fmaxf(flx,       0.f), 97.f);
        float tlyf = fminf(fmaxf(fly,       0.f), 97.f);
        float brxf = fminf(fmaxf(flx + 1.f, 0.f), 97.f);
        float bryf = fminf(fmaxf(fly + 1.f, 0.f), 97.f);
        float pcx  = fminf(fmaxf(px, 0.f), 97.f);
        float pcy  = fminf(fmaxf(py, 0.f), 97.f);
        float gx0 = 1.f + tlxf - pcx;
        float gx1 = 1.f - (brxf - pcx);
        float gy0 = 1.f + tlyf - pcy;
        float gy1 = 1.f - (bryf - pcy);
        int tlx = (int)tlxf, tly = (int)tlyf, brx = (int)brxf, bry = (int)bryf;
        int   qxs[4] = {tlx, tlx, brx, brx};
        int   qys[4] = {tly, bry, tly, bry};
        float gs[4]  = {gx0 * gy0, gx0 * gy1, gx1 * gy0, gx1 * gy1};
        int   idx[4]; float gg[4];
        #pragma unroll
        for (int c4 = 0; c4 < 4; ++c4) {
            bool okc = (qxs[c4] >= 1) && (qxs[c4] <= 96) && (qys[c4] >= 1) && (qys[c4] <= 96);
            idx[c4] = okc ? ((qxs[c4] - 1) * W_ + (qys[c4] - 1)) : 0;
            gg[c4]  = okc ? gs[c4] * mod : 0.f;
        }
        int4 iv;   iv.x = idx[0]; iv.y = idx[1]; iv.z = idx[2]; iv.w = idx[3];
        float4 gv; gv.x = gg[0];  gv.y = gg[1];  gv.z = gg[2];  gv.w = gg[3];
        *(int4*)  (mp + n * 8)     = iv;
        *(float4*)(mp + n * 8 + 4) = gv;
    }
}

// ---------------------------------------------------------------------------
// Main contraction as MFMA GEMM (M=64, K=576, N=64 pixels/block).
__global__ __launch_bounds__(256, 2) void k_main2(const unsigned short* __restrict__ xt,
                                                  const float* __restrict__ meta,
                                                  const unsigned short* __restrict__ wfm,
                                                  const float* __restrict__ convb,
                                                  float* __restrict__ out) {
    __shared__ unsigned short s_tile[64 * 72];
    int tid = threadIdx.x, blk = blockIdx.x;
    int b = blk / 144, s0 = (blk % 144) * 64;
    int p = tid & 63, q = tid >> 6;
    int lane = p, w = q, quad = lane >> 4;
    const unsigned short* xtb = xt + (size_t)b * HW_ * 64;
    const float* mpB = meta + (size_t)(blk * 64 + p) * 72;

    floatx4 acc[4];
    #pragma unroll
    for (int mt = 0; mt < 4; ++mt) acc[mt] = (floatx4){0.f, 0.f, 0.f, 0.f};

    #pragma unroll 1
    for (int n = 0; n < 9; ++n) {
        int4   idx = *(const int4*)  (mpB + n * 8);
        float4 g   = *(const float4*)(mpB + n * 8 + 4);
        int   cidx[4] = {idx.x, idx.y, idx.z, idx.w};
        float gw[4]   = {g.x, g.y, g.z, g.w};
        ushort8 cv[4][2];
        #pragma unroll
        for (int cn = 0; cn < 4; ++cn) {
            const ushort8* pc = (const ushort8*)(xtb + (size_t)cidx[cn] * 64 + q * 16);
            cv[cn][0] = pc[0];
            cv[cn][1] = pc[1];
        }
        ushort8 ov[2];
        #pragma unroll
        for (int h = 0; h < 2; ++h) {
            #pragma unroll
            for (int j = 0; j < 8; ++j) {
                float a = gw[0] * bf2f(cv[0][h][j]);
                a = fmaf(gw[1], bf2f(cv[1][h][j]), a);
                a = fmaf(gw[2], bf2f(cv[2][h][j]), a);
                a = fmaf(gw[3], bf2f(cv[3][h][j]), a);
                ov[h][j] = f2bf(a);
            }
        }
        __syncthreads();
        *(ushort8*)&s_tile[p * 72 + q * 16]     = ov[0];
        *(ushort8*)&s_tile[p * 72 + q * 16 + 8] = ov[1];
        __syncthreads();
        #pragma unroll
        for (int ksl = 0; ksl < 2; ++ksl) {
            int ks = n * 2 + ksl;
            bf16x8 bfrag = *(const bf16x8*)&s_tile[(w * 16 + (lane & 15)) * 72 + ksl * 32 + quad * 8];
            #pragma unroll
            for (int mt = 0; mt < 4; ++mt) {
                bf16x8 afrag = *(const bf16x8*)(wfm + ((size_t)(ks * 4 + mt) * 64 + lane) * 8);
                acc[mt] = __builtin_amdgcn_mfma_f32_16x16x32_bf16(afrag, bfrag, acc[mt], 0, 0, 0);
            }
        }
    }

    int pp = w * 16 + (lane & 15);
    size_t obase = (size_t)b * O_ * HW_ + s0 + pp;
    #pragma unroll
    for (int mt = 0; mt < 4; ++mt) {
        #pragma unroll
        for (int r = 0; r < 4; ++r) {
            int o = mt * 16 + quad * 4 + r;
            out[obase + (size_t)o * HW_] = acc[mt][r] + convb[o];
        }
    }
}

// ---------------------------------------------------------------------------
extern "C" void kernel_launch(void* const* d_in, const int* in_sizes, int n_in,
                              void* d_out, int out_size, void* d_ws, size_t ws_size,
                              hipStream_t stream) {
    const float* x     = (const float*)d_in[0];
    const float* offw  = (const float*)d_in[1];
    const float* offb  = (const float*)d_in[2];
    const float* mw    = (const float*)d_in[3];
    const float* mb    = (const float*)d_in[4];
    const float* convw = (const float*)d_in[5];
    const float* convb = (const float*)d_in[6];
    char* ws = (char*)d_ws;
    unsigned short* xt16 = (unsigned short*)(ws + XT_OFF);
    float*          meta = (float*)(ws + META_OFF);
    unsigned short* wfm  = (unsigned short*)(ws + WFM_OFF);
    unsigned short* wfo  = (unsigned short*)(ws + WFO_OFF);
    float* out = (float*)d_out;

    k_transpose<<<dim3(1152), dim3(256), 0, stream>>>(x, xt16);
    k_prepw    <<<dim3(27),   dim3(256), 0, stream>>>(offw, mw, convw, wfm, wfo);
    k_offs2    <<<dim3(1152), dim3(256), 0, stream>>>(xt16, wfo, offb, mb, meta);
    k_main2    <<<dim3(1152), dim3(256), 0, stream>>>(xt16, meta, wfm, convb, out);
}

// Round 3
// 146.628 us; speedup vs baseline: 3.2377x; 1.1942x over previous
//
#include <hip/hip_runtime.h>
#include <cstddef>

#define B_   8
#define H_   96
#define W_   96
#define HW_  9216
#define PIX_ 73728

typedef __attribute__((ext_vector_type(8))) __bf16 bf16x8;
typedef __attribute__((ext_vector_type(4))) float floatx4;
typedef __attribute__((ext_vector_type(8))) unsigned short ushort8;

// ws layout (byte offsets)
#define XT_OFF   0                          // bf16 NHWC x: PIX*64*2
#define WFM_OFF  (XT_OFF + PIX_*64*2)       // main W frags: 18*4*64*8 bf16
#define WFO_OFF  (WFM_OFF + 18*4*64*8*2)    // offs W frags: 18*2*64*8 bf16

__device__ __forceinline__ unsigned short f2bf(float f) {
    unsigned u = __float_as_uint(f);
    return (unsigned short)((u + 0x7FFFu + ((u >> 16) & 1u)) >> 16);
}
__device__ __forceinline__ float bf2f(unsigned short v) {
    return __uint_as_float((unsigned)v << 16);
}

// ---------------------------------------------------------------------------
// NCHW f32 -> NHWC bf16 transpose via LDS tile
__global__ __launch_bounds__(256) void k_transpose(const float* __restrict__ x,
                                                   unsigned short* __restrict__ xt) {
    __shared__ float tile[64 * 65];
    int bb  = blockIdx.x / 144;
    int sp0 = (blockIdx.x % 144) * 64;
    int t = threadIdx.x;
    int s = t & 63, cg = t >> 6;
    #pragma unroll
    for (int i = 0; i < 16; ++i) {
        int c = cg * 16 + i;
        tile[c * 65 + s] = x[(size_t)(bb * 64 + c) * HW_ + sp0 + s];
    }
    __syncthreads();
    int cl4 = (t & 15) * 4, sg = t >> 4;
    #pragma unroll
    for (int i = 0; i < 4; ++i) {
        int s2 = sg * 4 + i;
        uint2 wd;
        wd.x = (unsigned)f2bf(tile[cl4 * 65 + s2])       | ((unsigned)f2bf(tile[(cl4 + 1) * 65 + s2]) << 16);
        wd.y = (unsigned)f2bf(tile[(cl4 + 2) * 65 + s2]) | ((unsigned)f2bf(tile[(cl4 + 3) * 65 + s2]) << 16);
        *(uint2*)(xt + (size_t)(bb * HW_ + sp0 + s2) * 64 + cl4) = wd;
    }
}

// ---------------------------------------------------------------------------
// Pack weights into MFMA A-fragment order (k = tap*64 + c).
__global__ __launch_bounds__(256) void k_prepw(const float* __restrict__ offw,
                                               const float* __restrict__ mw,
                                               const float* __restrict__ convw,
                                               unsigned short* __restrict__ wfm,
                                               unsigned short* __restrict__ wfo) {
    int g = blockIdx.x * 256 + threadIdx.x;
    if (g < 4608) {
        int lane = g & 63, mtks = g >> 6;
        int mt = mtks & 3, ks = mtks >> 2;
        int o = mt * 16 + (lane & 15), quad = lane >> 4;
        unsigned v[8];
        #pragma unroll
        for (int j = 0; j < 8; ++j) {
            int k = ks * 32 + quad * 8 + j;
            int t = k / 64, c = k % 64;
            v[j] = f2bf(convw[(size_t)(o * 64 + c) * 9 + t]);
        }
        uint4 pk;
        pk.x = v[0] | (v[1] << 16); pk.y = v[2] | (v[3] << 16);
        pk.z = v[4] | (v[5] << 16); pk.w = v[6] | (v[7] << 16);
        *(uint4*)(wfm + (size_t)g * 8) = pk;
    } else if (g < 4608 + 2304) {
        int g2 = g - 4608;
        int lane = g2 & 63, mtks = g2 >> 6;
        int mt = mtks & 1, ks = mtks >> 1;
        int m = mt * 16 + (lane & 15), quad = lane >> 4;
        unsigned v[8];
        #pragma unroll
        for (int j = 0; j < 8; ++j) {
            int k = ks * 32 + quad * 8 + j;
            int t = k / 64, c = k % 64;
            float f = 0.f;
            if (m < 18)      f = offw[(size_t)(m * 64 + c) * 9 + t];
            else if (m < 27) f = mw[(size_t)((m - 18) * 64 + c) * 9 + t];
            v[j] = f2bf(f);
        }
        uint4 pk;
        pk.x = v[0] | (v[1] << 16); pk.y = v[2] | (v[3] << 16);
        pk.z = v[4] | (v[5] << 16); pk.w = v[6] | (v[7] << 16);
        *(uint4*)(wfo + (size_t)g2 * 8) = pk;
    }
}

// ---------------------------------------------------------------------------
// Fused: offset/mod conv (MFMA) -> bilinear meta -> main contraction (MFMA).
// One wave owns 32 pixels (2 B-frag column groups). No K-loop barriers.
__global__ __launch_bounds__(128) void k_fused(const unsigned short* __restrict__ xt,
                                               const unsigned short* __restrict__ wfo,
                                               const unsigned short* __restrict__ wfm,
                                               const float* __restrict__ offb,
                                               const float* __restrict__ mb,
                                               const float* __restrict__ convb,
                                               float* __restrict__ out) {
    __shared__ float s_off[2][32 * 33];     // [wave][m][pix] (stride 33)
    __shared__ float s_meta[2][32 * 72];    // [wave][pix][n][8 words]
    int tid = threadIdx.x;
    int w = tid >> 6, lane = tid & 63, col = lane & 15, quad = lane >> 4;
    int q8 = quad * 8;
    int pix0 = blockIdx.x * 64 + w * 32;
    int b  = pix0 / HW_;
    int sb = pix0 % HW_;
    const unsigned short* xtb = xt + (size_t)b * HW_ * 64;

    int sj[2], hj[2], wj[2];
    #pragma unroll
    for (int jj = 0; jj < 2; ++jj) {
        sj[jj] = sb + jj * 16 + col;
        hj[jj] = sj[jj] / 96; wj[jj] = sj[jj] % 96;
    }

    // ---- phase 1: offset/mod conv GEMM (M=32, K=576) ----
    floatx4 aoff[2][2];
    #pragma unroll
    for (int jj = 0; jj < 2; ++jj)
        #pragma unroll
        for (int mt = 0; mt < 2; ++mt) aoff[jj][mt] = (floatx4){0.f, 0.f, 0.f, 0.f};

    #pragma unroll 1
    for (int t = 0; t < 9; ++t) {
        int dh = t / 3 - 1, dw = t % 3 - 1;
        const unsigned short* pj[2]; bool okj[2];
        #pragma unroll
        for (int jj = 0; jj < 2; ++jj) {
            int h2 = hj[jj] + dh, w2 = wj[jj] + dw;
            okj[jj] = ((unsigned)h2 < 96u) && ((unsigned)w2 < 96u);
            pj[jj] = xtb + ((size_t)(h2 * 96 + w2) * 64 + q8);
        }
        #pragma unroll
        for (int ksl = 0; ksl < 2; ++ksl) {
            int ks = t * 2 + ksl;
            bf16x8 a0 = *(const bf16x8*)(wfo + ((size_t)(ks * 2 + 0) * 64 + lane) * 8);
            bf16x8 a1 = *(const bf16x8*)(wfo + ((size_t)(ks * 2 + 1) * 64 + lane) * 8);
            #pragma unroll
            for (int jj = 0; jj < 2; ++jj) {
                uint4 bv = make_uint4(0, 0, 0, 0);
                if (okj[jj]) bv = *(const uint4*)(pj[jj] + ksl * 32);
                union { uint4 u; bf16x8 b; } uu; uu.u = bv;
                aoff[jj][0] = __builtin_amdgcn_mfma_f32_16x16x32_bf16(a0, uu.b, aoff[jj][0], 0, 0, 0);
                aoff[jj][1] = __builtin_amdgcn_mfma_f32_16x16x32_bf16(a1, uu.b, aoff[jj][1], 0, 0, 0);
            }
        }
    }
    #pragma unroll
    for (int jj = 0; jj < 2; ++jj)
        #pragma unroll
        for (int mt = 0; mt < 2; ++mt)
            #pragma unroll
            for (int r = 0; r < 4; ++r)
                s_off[w][(mt * 16 + quad * 4 + r) * 33 + jj * 16 + col] = aoff[jj][mt][r];
    __syncthreads();

    // ---- phase 2: bilinear metadata (per-wave pixels only) ----
    int gl = lane >> 5;            // 0..1
    int pp = lane & 31;
    int sP = sb + pp, hh = sP / 96, ww = sP % 96;
    #pragma unroll
    for (int i = 0; i < 5; ++i) {
        int n = gl + 2 * i;
        if (n <= 8) {
            float ox = s_off[w][n * 33 + pp]        + offb[n];
            float oy = s_off[w][(9 + n) * 33 + pp]  + offb[9 + n];
            float mv = s_off[w][(18 + n) * 33 + pp] + mb[n];
            float mod = 1.f / (1.f + __expf(-mv));
            float px = ox + (float)(hh + 1) + (float)(n / 3 - 1);
            float py = oy + (float)(ww + 1) + (float)(n % 3 - 1);
            float flx = floorf(px), fly = floorf(py);
            float tlxf = fminf(fmaxf(flx,       0.f), 97.f);
            float tlyf = fminf(fmaxf(fly,       0.f), 97.f);
            float brxf = fminf(fmaxf(flx + 1.f, 0.f), 97.f);
            float bryf = fminf(fmaxf(fly + 1.f, 0.f), 97.f);
            float pcx  = fminf(fmaxf(px, 0.f), 97.f);
            float pcy  = fminf(fmaxf(py, 0.f), 97.f);
            float gx0 = 1.f + tlxf - pcx;
            float gx1 = 1.f - (brxf - pcx);
            float gy0 = 1.f + tlyf - pcy;
            float gy1 = 1.f - (bryf - pcy);
            int tlx = (int)tlxf, tly = (int)tlyf, brx = (int)brxf, bry = (int)bryf;
            int   qxs[4] = {tlx, tlx, brx, brx};
            int   qys[4] = {tly, bry, tly, bry};
            float gs[4]  = {gx0 * gy0, gx0 * gy1, gx1 * gy0, gx1 * gy1};
            int   idx[4]; float gg[4];
            #pragma unroll
            for (int c4 = 0; c4 < 4; ++c4) {
                bool okc = (qxs[c4] >= 1) && (qxs[c4] <= 96) && (qys[c4] >= 1) && (qys[c4] <= 96);
                idx[c4] = okc ? ((qxs[c4] - 1) * W_ + (qys[c4] - 1)) : 0;
                gg[c4]  = okc ? gs[c4] * mod : 0.f;
            }
            int4 iv;   iv.x = idx[0]; iv.y = idx[1]; iv.z = idx[2]; iv.w = idx[3];
            float4 gv; gv.x = gg[0];  gv.y = gg[1];  gv.z = gg[2];  gv.w = gg[3];
            *(int4*)  &s_meta[w][pp * 72 + n * 8]     = iv;
            *(float4*)&s_meta[w][pp * 72 + n * 8 + 4] = gv;
        }
    }
    __syncthreads();

    // ---- phase 3: main contraction GEMM (M=64, K=576), direct-frag gather ----
    floatx4 acc[2][4];
    #pragma unroll
    for (int jj = 0; jj < 2; ++jj)
        #pragma unroll
        for (int mt = 0; mt < 4; ++mt) acc[jj][mt] = (floatx4){0.f, 0.f, 0.f, 0.f};

    #pragma unroll 1
    for (int n = 0; n < 9; ++n) {
        int4 idx[2]; float4 g4[2];
        #pragma unroll
        for (int jj = 0; jj < 2; ++jj) {
            int mo = (jj * 16 + col) * 72 + n * 8;
            idx[jj] = *(const int4*)  &s_meta[w][mo];
            g4[jj]  = *(const float4*)&s_meta[w][mo + 4];
        }
        #pragma unroll
        for (int ksl = 0; ksl < 2; ++ksl) {
            int ks = n * 2 + ksl;
            int cb = ksl * 32 + q8;
            bf16x8 af[4];
            #pragma unroll
            for (int mt = 0; mt < 4; ++mt)
                af[mt] = *(const bf16x8*)(wfm + ((size_t)(ks * 4 + mt) * 64 + lane) * 8);
            #pragma unroll
            for (int jj = 0; jj < 2; ++jj) {
                ushort8 c0 = *(const ushort8*)(xtb + (size_t)idx[jj].x * 64 + cb);
                ushort8 c1 = *(const ushort8*)(xtb + (size_t)idx[jj].y * 64 + cb);
                ushort8 c2 = *(const ushort8*)(xtb + (size_t)idx[jj].z * 64 + cb);
                ushort8 c3 = *(const ushort8*)(xtb + (size_t)idx[jj].w * 64 + cb);
                float gx = g4[jj].x, gy = g4[jj].y, gz = g4[jj].z, gw = g4[jj].w;
                ushort8 ov;
                #pragma unroll
                for (int j = 0; j < 8; ++j) {
                    float v = gx * bf2f(c0[j]);
                    v = fmaf(gy, bf2f(c1[j]), v);
                    v = fmaf(gz, bf2f(c2[j]), v);
                    v = fmaf(gw, bf2f(c3[j]), v);
                    ov[j] = f2bf(v);
                }
                union { ushort8 u; bf16x8 b; } ub; ub.u = ov;
                #pragma unroll
                for (int mt = 0; mt < 4; ++mt)
                    acc[jj][mt] = __builtin_amdgcn_mfma_f32_16x16x32_bf16(af[mt], ub.b, acc[jj][mt], 0, 0, 0);
            }
        }
    }

    // ---- epilogue ----
    #pragma unroll
    for (int mt = 0; mt < 4; ++mt) {
        float4 cb4 = *(const float4*)&convb[mt * 16 + quad * 4];
        #pragma unroll
        for (int jj = 0; jj < 2; ++jj) {
            #pragma unroll
            for (int r = 0; r < 4; ++r) {
                int o = mt * 16 + quad * 4 + r;
                float bias = (r == 0) ? cb4.x : (r == 1) ? cb4.y : (r == 2) ? cb4.z : cb4.w;
                out[(size_t)(b * 64 + o) * HW_ + sj[jj]] = acc[jj][mt][r] + bias;
            }
        }
    }
}

// ---------------------------------------------------------------------------
extern "C" void kernel_launch(void* const* d_in, const int* in_sizes, int n_in,
                              void* d_out, int out_size, void* d_ws, size_t ws_size,
                              hipStream_t stream) {
    const float* x     = (const float*)d_in[0];
    const float* offw  = (const float*)d_in[1];
    const float* offb  = (const float*)d_in[2];
    const float* mw    = (const float*)d_in[3];
    const float* mb    = (const float*)d_in[4];
    const float* convw = (const float*)d_in[5];
    const float* convb = (const float*)d_in[6];
    char* ws = (char*)d_ws;
    unsigned short* xt16 = (unsigned short*)(ws + XT_OFF);
    unsigned short* wfm  = (unsigned short*)(ws + WFM_OFF);
    unsigned short* wfo  = (unsigned short*)(ws + WFO_OFF);
    float* out = (float*)d_out;

    k_transpose<<<dim3(1152), dim3(256), 0, stream>>>(x, xt16);
    k_prepw    <<<dim3(27),   dim3(256), 0, stream>>>(offw, mw, convw, wfm, wfo);
    k_fused    <<<dim3(1152), dim3(128), 0, stream>>>(xt16, wfo, wfm, offb, mb, convb, out);
}